// Round 19
// baseline (326.112 us; speedup 1.0000x reference)
//
#include <hip/hip_runtime.h>
#include <stdint.h>

typedef unsigned short u16;
typedef __bf16 bf16x8_t __attribute__((ext_vector_type(8)));
typedef float f32x4_t __attribute__((ext_vector_type(4)));

#define T_SEQ 2048
#define HID 4096
#define ROWQKV 6144

__device__ __forceinline__ float bf2f(u16 x){ return __uint_as_float(((uint32_t)x)<<16); }
__device__ __forceinline__ u16 f2bf(float f){
  uint32_t u = __float_as_uint(f);
  return (u16)((u + 0x7fffu + ((u>>16)&1u)) >> 16);
}

__device__ __forceinline__ void gload16(const void* g, void* l){
  __builtin_amdgcn_global_load_lds(
      (const __attribute__((address_space(1))) uint32_t*)g,
      (__attribute__((address_space(3))) uint32_t*)l, 16, 0, 0);
}

__device__ __forceinline__ uint32_t cvtpk(float lo, float hi_){
  uint32_t r;
  asm("v_cvt_pk_bf16_f32 %0, %1, %2" : "=v"(r) : "v"(lo), "v"(hi_));
  return r;
}

// ------- fused fp32 -> bf16 conversion for hs + Wq + Wk + Wv + Wo (1 launch)
__global__ void cvt_all(const float* __restrict__ hs, const float* __restrict__ Wq,
                        const float* __restrict__ Wk, const float* __restrict__ Wv,
                        const float* __restrict__ Wo, u16* __restrict__ hs_bf,
                        u16* __restrict__ Wqkv_bf, u16* __restrict__ Wo_bf){
  int i = blockIdx.x*blockDim.x + threadIdx.x;   // 6291456 threads
  const float* s; u16* d;
  if (i < 1048576)      { s = hs + (size_t)i*8;            d = hs_bf  + (size_t)i*8; }
  else if (i < 3145728) { size_t j = i - 1048576; s = Wq + j*8; d = Wqkv_bf + j*8; }
  else if (i < 3670016) { size_t j = i - 3145728; s = Wk + j*8; d = Wqkv_bf + (size_t)(2097152 + j)*8; }
  else if (i < 4194304) { size_t j = i - 3670016; s = Wv + j*8; d = Wqkv_bf + (size_t)(2621440 + j)*8; }
  else                  { size_t j = i - 4194304; s = Wo + j*8; d = Wo_bf + j*8; }
  float4 a = *(const float4*)s, b = *(const float4*)(s + 4);
  union { u16 u[8]; uint4 v; } o;
  o.u[0]=f2bf(a.x); o.u[1]=f2bf(a.y); o.u[2]=f2bf(a.z); o.u[3]=f2bf(a.w);
  o.u[4]=f2bf(b.x); o.u[5]=f2bf(b.y); o.u[6]=f2bf(b.z); o.u[7]=f2bf(b.w);
  *(uint4*)d = o.v;
}

// ---------------- bias concat + rope tables ----------------
__global__ void setup_kernel(const float* __restrict__ bq, const float* __restrict__ bk,
                             const float* __restrict__ bv, const int* __restrict__ pos,
                             float* __restrict__ bqkv, float* __restrict__ cost,
                             float* __restrict__ sint){
  int i = blockIdx.x*blockDim.x + threadIdx.x;
  if (i < 6144) bqkv[i] = (i<4096) ? bq[i] : ((i<5120) ? bk[i-4096] : bv[i-5120]);
  if (i < T_SEQ*64){
    int t = i >> 6, d = i & 63;
    float inv = powf(10000.0f, -(float)(2*d) / 128.0f);
    float ang = (float)pos[t] * inv;
    cost[i] = cosf(ang);
    sint[i] = sinf(ang);
  }
}

#define GBAR __builtin_amdgcn_s_barrier()
#define LGKM0 do{ asm volatile("s_waitcnt lgkmcnt(0)" ::: "memory"); \
                  __builtin_amdgcn_sched_barrier(0); }while(0)

// ------- GEMM 256x192 4-phase (full-fill QKV): C = A[M,K]*B[N,K]^T + bias ---
#define BUF6 28672   // elems per buffer (A 16384 + B 12288)

#define AREAD6(mh, ck) do{ \
  const u16* ab = &lds[cur + aoff + (mh)*4096]; \
  afr[0] = *(const bf16x8_t*)&ab[0*1024 + (ck)]; \
  afr[1] = *(const bf16x8_t*)&ab[1*1024 + (ck)]; \
  afr[2] = *(const bf16x8_t*)&ab[2*1024 + (ck)]; \
  afr[3] = *(const bf16x8_t*)&ab[3*1024 + (ck)]; }while(0)

#define BREAD6(ck) do{ \
  const u16* bb = &lds[cur + boff]; \
  bfr[0] = *(const bf16x8_t*)&bb[0*1024 + (ck)]; \
  bfr[1] = *(const bf16x8_t*)&bb[1*1024 + (ck)]; \
  bfr[2] = *(const bf16x8_t*)&bb[2*1024 + (ck)]; }while(0)

#define MM12(mh) do{ \
  _Pragma("unroll") \
  for (int mi=0; mi<4; ++mi){ \
    _Pragma("unroll") \
    for (int n=0; n<3; ++n) \
      acc[(mh)*4+mi][n] = __builtin_amdgcn_mfma_f32_16x16x32_bf16(afr[mi], bfr[n], acc[(mh)*4+mi][n],0,0,0); \
  } }while(0)

__global__ __launch_bounds__(512, 2)
void gemm_qkv(const u16* __restrict__ A, const u16* __restrict__ B,
              const float* __restrict__ bias, u16* __restrict__ Cb,
              int K, int N)
{
  __shared__ u16 lds[2*BUF6];
  const int tid = threadIdx.x, lane = tid & 63, w = tid >> 6;
  const int l15 = lane & 15, l4 = lane >> 4;
  const int wm = w >> 2, wn = w & 3;

  const int nwg = gridDim.x * gridDim.y;   // 256
  int flat = blockIdx.y * gridDim.x + blockIdx.x;
  flat = (flat & 7) * (nwg >> 3) + (flat >> 3);
  const int bx = flat % gridDim.x, by = flat / gridDim.x;
  const int bm = by * 256, bn = bx * 192;

  const int srow = w*8 + (lane >> 3);
  const int swc  = ((lane & 7) ^ (lane >> 3)) * 8;
  const u16* pA = A + (size_t)(bm + srow)*K + swc;
  const u16* pB = B + (size_t)(bn + srow)*K + swc;
  const size_t j64 = (size_t)64*K;
  const int wu = w*512;

  const int cA0 = ((0 + l4) ^ (l15 & 7)) * 8;
  const int cA1 = ((4 + l4) ^ (l15 & 7)) * 8;
  const int aoff = (wm*128 + l15) * 64;
  const int boff = 16384 + (wn*48 + l15) * 64;

  f32x4_t acc[8][3] = {};
  const int KT = K >> 6;

  gload16(pA + 0*j64, &lds[0     + wu]);
  gload16(pA + 1*j64, &lds[4096  + wu]);
  gload16(pA + 2*j64, &lds[8192  + wu]);
  gload16(pA + 3*j64, &lds[12288 + wu]);
  gload16(pB + 0*j64, &lds[16384 + wu]);
  gload16(pB + 1*j64, &lds[20480 + wu]);
  gload16(pB + 2*j64, &lds[24576 + wu]);
  pA += 64; pB += 64;
  asm volatile("s_waitcnt vmcnt(0)" ::: "memory");
  GBAR;

  for (int t = 0; t < KT; ++t){
    const int cur = (t & 1) * BUF6;
    const int nxt = ((t + 1) & 1) * BUF6;
    const bool st = (t + 1 < KT);
    bf16x8_t afr[4], bfr[3];

    BREAD6(cA0); AREAD6(0, cA0);
    if (st){
      gload16(pA + 0*j64, &lds[nxt + 0     + wu]);
      gload16(pA + 1*j64, &lds[nxt + 4096  + wu]);
      gload16(pA + 2*j64, &lds[nxt + 8192  + wu]);
      gload16(pA + 3*j64, &lds[nxt + 12288 + wu]);
    }
    GBAR; LGKM0;
    __builtin_amdgcn_s_setprio(1); MM12(0); __builtin_amdgcn_s_setprio(0);
    GBAR;

    AREAD6(1, cA0);
    if (st){
      gload16(pB + 0*j64, &lds[nxt + 16384 + wu]);
      gload16(pB + 1*j64, &lds[nxt + 20480 + wu]);
      gload16(pB + 2*j64, &lds[nxt + 24576 + wu]);
      pA += 64; pB += 64;
    }
    GBAR; LGKM0;
    __builtin_amdgcn_s_setprio(1); MM12(1); __builtin_amdgcn_s_setprio(0);
    GBAR;

    BREAD6(cA1); AREAD6(0, cA1);
    GBAR; LGKM0;
    __builtin_amdgcn_s_setprio(1); MM12(0); __builtin_amdgcn_s_setprio(0);
    GBAR;

    AREAD6(1, cA1);
    GBAR; LGKM0;
    __builtin_amdgcn_s_setprio(1); MM12(1); __builtin_amdgcn_s_setprio(0);
    if (st) asm volatile("s_waitcnt vmcnt(0)" ::: "memory");
    GBAR;
  }

  #pragma unroll
  for (int m=0;m<8;m++){
    #pragma unroll
    for (int n=0;n<3;n++){
      #pragma unroll
      for (int j=0;j<4;j++){
        int row = bm + wm*128 + (m>>2)*64 + (m&3)*16 + l4*4 + j;
        int col = bn + wn*48 + n*16 + l15;
        Cb[(size_t)row*N + col] = f2bf(acc[m][n][j] + bias[col]);
      }
    }
  }
}

// ------- GEMM 256x128 2-phase tri-buffer (full-fill O-proj variant) ---------
#define BUFK 24576   // elems per buffer (A 16384 + B 8192)

#define KMREAD(ck) do{ \
  afr[0] = *(const bf16x8_t*)&lds[cur + aoff + 0*1024 + (ck)]; \
  afr[1] = *(const bf16x8_t*)&lds[cur + aoff + 1*1024 + (ck)]; \
  afr[2] = *(const bf16x8_t*)&lds[cur + aoff + 2*1024 + (ck)]; \
  afr[3] = *(const bf16x8_t*)&lds[cur + aoff + 3*1024 + (ck)]; \
  bfr[0] = *(const bf16x8_t*)&lds[cur + boff + 0*1024 + (ck)]; \
  bfr[1] = *(const bf16x8_t*)&lds[cur + boff + 1*1024 + (ck)]; \
  bfr[2] = *(const bf16x8_t*)&lds[cur + boff + 2*1024 + (ck)]; \
  bfr[3] = *(const bf16x8_t*)&lds[cur + boff + 3*1024 + (ck)]; }while(0)

#define MM16KM do{ \
  _Pragma("unroll") \
  for (int mi=0; mi<4; ++mi){ \
    _Pragma("unroll") \
    for (int n=0; n<4; ++n) \
      acc[mi][n] = __builtin_amdgcn_mfma_f32_16x16x32_bf16(afr[mi], bfr[n], acc[mi][n],0,0,0); \
  } }while(0)

__global__ __launch_bounds__(512, 2)
void gemm_km(const u16* __restrict__ A, const u16* __restrict__ B,
             const float* __restrict__ bias, float* __restrict__ Cf,
             int K, int N)
{
  __shared__ u16 lds[3*BUFK];
  const int tid = threadIdx.x, lane = tid & 63, w = tid >> 6;
  const int l15 = lane & 15, l4 = lane >> 4;
  const int wm = w >> 1, wn = w & 1;

  const int nwg = gridDim.x * gridDim.y;   // 256
  int flat = blockIdx.y * gridDim.x + blockIdx.x;
  flat = (flat & 7) * (nwg >> 3) + (flat >> 3);
  const int bx = flat % gridDim.x, by = flat / gridDim.x;
  const int bm = by * 256, bn = bx * 128;

  const int srow = w*8 + (lane >> 3);
  const int swc  = ((lane & 7) ^ (lane >> 3)) * 8;
  const u16* pA = A + (size_t)(bm + srow)*K + swc;
  const u16* pB = B + (size_t)(bn + srow)*K + swc;
  const size_t j64 = (size_t)64*K;
  const int wu = w*512;

  const int cA0 = ((0 + l4) ^ (l15 & 7)) * 8;
  const int cA1 = ((4 + l4) ^ (l15 & 7)) * 8;
  const int aoff = (wm*64 + l15) * 64;
  const int boff = 16384 + (wn*64 + l15) * 64;

  f32x4_t acc[4][4] = {};
  const int KT = K >> 6;

  gload16(pA + 0*j64,      &lds[0*4096 + wu]);
  gload16(pA + 1*j64,      &lds[1*4096 + wu]);
  gload16(pA + 2*j64,      &lds[2*4096 + wu]);
  gload16(pA + 3*j64,      &lds[3*4096 + wu]);
  gload16(pB + 0*j64,      &lds[16384 + 0*4096 + wu]);
  gload16(pB + 1*j64,      &lds[16384 + 1*4096 + wu]);
  gload16(pA + 64 + 0*j64, &lds[BUFK + 0*4096 + wu]);
  gload16(pA + 64 + 1*j64, &lds[BUFK + 1*4096 + wu]);
  gload16(pA + 64 + 2*j64, &lds[BUFK + 2*4096 + wu]);
  gload16(pA + 64 + 3*j64, &lds[BUFK + 3*4096 + wu]);
  gload16(pB + 64 + 0*j64, &lds[BUFK + 16384 + 0*4096 + wu]);
  gload16(pB + 64 + 1*j64, &lds[BUFK + 16384 + 1*4096 + wu]);
  pA += 128; pB += 128;
  asm volatile("s_waitcnt vmcnt(6)" ::: "memory");
  GBAR;

  for (int t = 0; t < KT; ++t){
    const int cur = (t % 3) * BUFK;
    const int sb  = ((t + 2) % 3) * BUFK;
    const bool st = (t + 2 < KT);
    bf16x8_t afr[4], bfr[4];

    KMREAD(cA0);
    if (st){
      gload16(pA + 0*j64, &lds[sb + 0*4096 + wu]);
      gload16(pA + 1*j64, &lds[sb + 1*4096 + wu]);
      gload16(pA + 2*j64, &lds[sb + 2*4096 + wu]);
    }
    GBAR; LGKM0;
    __builtin_amdgcn_s_setprio(1); MM16KM; __builtin_amdgcn_s_setprio(0);
    GBAR;

    KMREAD(cA1);
    if (st){
      gload16(pA + 3*j64, &lds[sb + 3*4096 + wu]);
      gload16(pB + 0*j64, &lds[sb + 16384 + 0*4096 + wu]);
      gload16(pB + 1*j64, &lds[sb + 16384 + 1*4096 + wu]);
      pA += 64; pB += 64;
    }
    GBAR; LGKM0;
    __builtin_amdgcn_s_setprio(1); MM16KM; __builtin_amdgcn_s_setprio(0);
    if (st)              asm volatile("s_waitcnt vmcnt(6)" ::: "memory");
    else if (t + 1 < KT) asm volatile("s_waitcnt vmcnt(0)" ::: "memory");
    GBAR;
  }

  #pragma unroll
  for (int mi=0;mi<4;mi++){
    #pragma unroll
    for (int n=0;n<4;n++){
      #pragma unroll
      for (int j=0;j<4;j++){
        int row = bm + wm*64 + mi*16 + l4*4 + j;
        int col = bn + wn*64 + n*16 + l15;
        Cf[(size_t)row*N + col] = acc[mi][n][j] + bias[col];
      }
    }
  }
}

// ---------------- RoPE in-place on q (heads 0..31) and k (heads 32..39) -----
__global__ void rope_kernel(u16* __restrict__ qkv, const float* __restrict__ cost,
                            const float* __restrict__ sint){
  int i = blockIdx.x*blockDim.x + threadIdx.x;
  int t = i / 2560;
  int r = i % 2560;
  int h = r >> 6, d = r & 63;
  int base = (h < 32) ? h*128 : (4096 + (h-32)*128);
  size_t p1 = (size_t)t*ROWQKV + base + d;
  float x1 = bf2f(qkv[p1]), x2 = bf2f(qkv[p1+64]);
  float c = cost[(t<<6)+d], s = sint[(t<<6)+d];
  qkv[p1]    = f2bf(x1*c - x2*s);
  qkv[p1+64] = f2bf(x2*c + x1*s);
}

// ---------------- flash attention (r16 + exact skip of no-growth rescale) ---
#define VOFF 16384
#define POFF 25600

__global__ __launch_bounds__(256, 2)
void attn_kernel(const u16* __restrict__ qkv, u16* __restrict__ attn_o)
{
  __shared__ u16 lds[29696];   // 58 KB
  const int tid = threadIdx.x, lane = tid&63, wid = tid>>6;
  const int l15 = lane&15, l4 = lane>>4;
  const int l7 = l15 & 7;
  const int h  = blockIdx.x & 31;
  const int qt = 31 - (blockIdx.x >> 5);       // heavy tiles first
  const int q0 = qt * 64;
  const int kvh = h >> 2;
  const u16* Qg = qkv + h*128;
  const u16* Kg = qkv + 4096 + kvh*128;
  const u16* Vg = qkv + 5120 + kvh*128;
  const float c2 = 0.127543147f;               // (1/sqrt(128)) * log2(e)

  bf16x8_t qf[4];
  {
    size_t qrow = (size_t)(q0 + wid*16 + l15);
    #pragma unroll
    for (int kk=0;kk<4;kk++)
      qf[kk] = *(const bf16x8_t*)(Qg + qrow*ROWQKV + kk*32 + l4*8);
  }
  float mrow[4] = {-1e30f,-1e30f,-1e30f,-1e30f};   // raw-score units
  float mc[4]   = {-1e30f,-1e30f,-1e30f,-1e30f};   // mrow * c2 (cached)
  f32x4_t oacc[9] = {};                            // [8] = row-sum (ones col)

  const u16* ksrc[4];
  int kls[4];
  #pragma unroll
  for (int i=0;i<4;i++){
    const int c = wid*4 + i;
    ksrc[i] = Kg + (size_t)((c&7)*8 + (lane>>3))*ROWQKV
               + (c>>3)*64 + ((lane&7)^(lane>>3))*8;
    kls[i] = c*512;
  }
  const int kvp = tid & 31;
  const int vd0 = (tid >> 5) * 16;
  uint4 rv[4];

  #pragma unroll
  for (int i=0;i<4;i++) gload16(ksrc[i], &lds[kls[i]]);
  #pragma unroll
  for (int i=0;i<4;i++) ksrc[i] += (size_t)64*ROWQKV;
  {
    const u16* va = Vg + (size_t)(2*kvp)*ROWQKV + vd0;
    rv[0] = *(const uint4*)va;            rv[1] = *(const uint4*)(va + 8);
    rv[2] = *(const uint4*)(va + ROWQKV); rv[3] = *(const uint4*)(va + ROWQKV + 8);
    *(uint32_t*)&lds[24576 + tid*4]     = 0x3F803F80u;
    *(uint32_t*)&lds[24576 + tid*4 + 2] = 0x3F803F80u;
  }
  __syncthreads();
  {
    const u16* ra = (const u16*)&rv[0]; const u16* rb = (const u16*)&rv[2];
    #pragma unroll
    for (int e=0;e<8;e++)
      *(uint32_t*)&lds[VOFF + (vd0+e)*64 + ((kvp>>2)^(e&7))*8 + 2*(kvp&3)]
          = (uint32_t)ra[e] | ((uint32_t)rb[e] << 16);
    ra = (const u16*)&rv[1]; rb = (const u16*)&rv[3];
    #pragma unroll
    for (int e=0;e<8;e++)
      *(uint32_t*)&lds[VOFF + (vd0+8+e)*64 + ((kvp>>2)^(e&7))*8 + 2*(kvp&3)]
          = (uint32_t)ra[e] | ((uint32_t)rb[e] << 16);
  }
  __syncthreads();

  for (int kt = 0; kt <= qt; ++kt){
    const int kv0 = kt * 64;
    const int kcur = (kt & 1) * 8192;
    const bool pre = (kt < qt);
    if (pre){
      const int knxt = ((kt+1) & 1) * 8192;
      #pragma unroll
      for (int i=0;i<4;i++) gload16(ksrc[i], &lds[knxt + kls[i]]);
      #pragma unroll
      for (int i=0;i<4;i++) ksrc[i] += (size_t)64*ROWQKV;
      const u16* va = Vg + (size_t)(kv0 + 64 + 2*kvp)*ROWQKV + vd0;
      rv[0] = *(const uint4*)va;            rv[1] = *(const uint4*)(va + 8);
      rv[2] = *(const uint4*)(va + ROWQKV); rv[3] = *(const uint4*)(va + ROWQKV + 8);
    }

    // S = Q K^T (raw scores)
    f32x4_t sacc[4] = {};
    __builtin_amdgcn_s_setprio(1);
    #pragma unroll
    for (int n=0;n<4;n++){
      #pragma unroll
      for (int kk=0;kk<4;kk++){
        bf16x8_t kf = *(const bf16x8_t*)&lds[kcur + (kk>>1)*4096
                        + (n*16+l15)*64 + (((kk&1)*4 + l4) ^ l7)*8];
        sacc[n] = __builtin_amdgcn_mfma_f32_16x16x32_bf16(qf[kk], kf, sacc[n], 0,0,0);
      }
    }
    __builtin_amdgcn_s_setprio(0);
    float sv[4][4];
    float pmax[4] = {-1e30f,-1e30f,-1e30f,-1e30f};
    bool diag = (kt == qt);
    #pragma unroll
    for (int n=0;n<4;n++){
      int kvcol = kv0 + n*16 + l15;
      #pragma unroll
      for (int j=0;j<4;j++){
        float s = sacc[n][j];
        int qrow = q0 + wid*16 + l4*4 + j;
        if (diag && kvcol > qrow) s = -1e30f;
        sv[n][j] = s;
        pmax[j] = fmaxf(pmax[j], s);
      }
    }
    #pragma unroll
    for (int off=1; off<16; off<<=1){
      #pragma unroll
      for (int j=0;j<4;j++)
        pmax[j] = fmaxf(pmax[j], __shfl_xor(pmax[j], off, 64));
    }
    // rescale only when max actually grows (else esc == 1.0 exactly: skip)
    {
      bool grow = (pmax[0] > mrow[0]) || (pmax[1] > mrow[1])
               || (pmax[2] > mrow[2]) || (pmax[3] > mrow[3]);
      if (__any(grow)){
        float esc[4];
        #pragma unroll
        for (int j=0;j<4;j++){
          float mn = fmaxf(mrow[j], pmax[j]);
          esc[j] = exp2f((mrow[j] - mn) * c2);
          mrow[j] = mn;
          mc[j] = mn * c2;
        }
        #pragma unroll
        for (int n=0;n<9;n++){
          #pragma unroll
          for (int j=0;j<4;j++) oacc[n][j] *= esc[j];
        }
      }
    }
    #pragma unroll
    for (int n=0;n<4;n++){
      #pragma unroll
      for (int j=0;j<4;j++)
        sv[n][j] = exp2f(fmaf(sv[n][j], c2, -mc[j]));
    }
    // P -> LDS via cvt_pk, swizzled wave-private strip
    {
      const int r0 = wid*16 + l4*4;
      #pragma unroll
      for (int n=0;n<4;n++){
        uint32_t p01 = cvtpk(sv[n][0], sv[n][1]);
        uint32_t p23 = cvtpk(sv[n][2], sv[n][3]);
        const int cb = n*2 + (l15>>3);
        lds[POFF + (r0+0)*64 + ((cb ^ ((r0+0)&7))*8) + l7] = (u16)p01;
        lds[POFF + (r0+1)*64 + ((cb ^ ((r0+1)&7))*8) + l7] = (u16)(p01 >> 16);
        lds[POFF + (r0+2)*64 + ((cb ^ ((r0+2)&7))*8) + l7] = (u16)p23;
        lds[POFF + (r0+3)*64 + ((cb ^ ((r0+3)&7))*8) + l7] = (u16)(p23 >> 16);
      }
    }
    // O += P V  (n=8 reads the ones rows -> row-sum accumulates in oacc[8])
    __builtin_amdgcn_s_setprio(1);
    #pragma unroll
    for (int kk=0;kk<2;kk++){
      const int blk = ((kk*4 + l4) ^ l7)*8;
      bf16x8_t pf = *(const bf16x8_t*)&lds[POFF + (wid*16 + l15)*64 + blk];
      #pragma unroll
      for (int n=0;n<9;n++){
        bf16x8_t vf = *(const bf16x8_t*)&lds[VOFF + (n*16 + l15)*64 + blk];
        oacc[n] = __builtin_amdgcn_mfma_f32_16x16x32_bf16(pf, vf, oacc[n], 0,0,0);
      }
    }
    __builtin_amdgcn_s_setprio(0);
    __syncthreads();
    if (pre){
      const u16* ra = (const u16*)&rv[0]; const u16* rb = (const u16*)&rv[2];
      #pragma unroll
      for (int e=0;e<8;e++)
        *(uint32_t*)&lds[VOFF + (vd0+e)*64 + ((kvp>>2)^(e&7))*8 + 2*(kvp&3)]
            = (uint32_t)ra[e] | ((uint32_t)rb[e] << 16);
      ra = (const u16*)&rv[1]; rb = (const u16*)&rv[3];
      #pragma unroll
      for (int e=0;e<8;e++)
        *(uint32_t*)&lds[VOFF + (vd0+8+e)*64 + ((kvp>>2)^(e&7))*8 + 2*(kvp&3)]
            = (uint32_t)ra[e] | ((uint32_t)rb[e] << 16);
    }
    __syncthreads();
  }

  {
    float inv[4];
    #pragma unroll
    for (int j=0;j<4;j++) inv[j] = 1.0f / oacc[8][j];
    #pragma unroll
    for (int n=0;n<8;n++){
      #pragma unroll
      for (int j=0;j<4;j++){
        int qrow = q0 + wid*16 + l4*4 + j;
        int col  = h*128 + n*16 + l15;
        attn_o[(size_t)qrow*HID + col] = f2bf(oacc[n][j] * inv[j]);
      }
    }
  }
}

// ---------------- launcher ----------------
extern "C" void kernel_launch(void* const* d_in, const int* in_sizes, int n_in,
                              void* d_out, int out_size, void* d_ws, size_t ws_size,
                              hipStream_t stream)
{
  const float* hs = (const float*)d_in[0];
  const int*  pos = (const int*)d_in[1];
  const float* Wq = (const float*)d_in[2];
  const float* bq = (const float*)d_in[3];
  const float* Wk = (const float*)d_in[4];
  const float* bk = (const float*)d_in[5];
  const float* Wv = (const float*)d_in[6];
  const float* bv = (const float*)d_in[7];
  const float* Wo = (const float*)d_in[8];
  const float* bo = (const float*)d_in[9];
  float* out = (float*)d_out;

  char* ws = (char*)d_ws;
  u16* hs_bf   = (u16*)ws;  ws += (size_t)2048*4096*2;
  u16* Wqkv_bf = (u16*)ws;  ws += (size_t)6144*4096*2;
  u16* Wo_bf   = (u16*)ws;  ws += (size_t)4096*4096*2;
  u16* qkv     = (u16*)ws;  ws += (size_t)2048*6144*2;
  u16* attn_b  = (u16*)ws;  ws += (size_t)2048*4096*2;
  float* bqkv  = (float*)ws; ws += (size_t)6144*4;
  float* cost  = (float*)ws; ws += (size_t)2048*64*4;
  float* sint  = (float*)ws; ws += (size_t)2048*64*4;

  // all fp32 -> bf16 conversions in ONE dispatch (6291456 groups of 8)
  cvt_all<<<6291456/256, 256, 0, stream>>>(hs, Wq, Wk, Wv, Wo, hs_bf, Wqkv_bf, Wo_bf);
  setup_kernel<<<(T_SEQ*64 + 255)/256, 256, 0, stream>>>(bq, bk, bv, pos, bqkv, cost, sint);

  // QKV projection: [2048,6144] — 256x192 tiles, grid 32x8 = 256 blocks
  gemm_qkv<<<dim3(6144/192, 2048/256), 512, 0, stream>>>(hs_bf, Wqkv_bf, bqkv, qkv, 4096, 6144);
  // RoPE on q,k
  rope_kernel<<<(T_SEQ*40*64)/256, 256, 0, stream>>>(qkv, cost, sint);
  // attention
  attn_kernel<<<1024, 256, 0, stream>>>(qkv, attn_b);
  // output projection: [2048,4096] — 256x128 tiles, grid 32x8 = 256 blocks
  gemm_km<<<dim3(4096/128, 2048/256), 512, 0, stream>>>(attn_b, Wo_bf, bo, out, 4096, 4096);
}

// Round 20
// 323.902 us; speedup vs baseline: 1.0068x; 1.0068x over previous
//
#include <hip/hip_runtime.h>
#include <stdint.h>

typedef unsigned short u16;
typedef __bf16 bf16x8_t __attribute__((ext_vector_type(8)));
typedef float f32x4_t __attribute__((ext_vector_type(4)));

#define T_SEQ 2048
#define HID 4096
#define ROWQKV 6144

__device__ __forceinline__ float bf2f(u16 x){ return __uint_as_float(((uint32_t)x)<<16); }
__device__ __forceinline__ u16 f2bf(float f){
  uint32_t u = __float_as_uint(f);
  return (u16)((u + 0x7fffu + ((u>>16)&1u)) >> 16);
}

__device__ __forceinline__ void gload16(const void* g, void* l){
  __builtin_amdgcn_global_load_lds(
      (const __attribute__((address_space(1))) uint32_t*)g,
      (__attribute__((address_space(3))) uint32_t*)l, 16, 0, 0);
}

__device__ __forceinline__ uint32_t cvtpk(float lo, float hi_){
  uint32_t r;
  asm("v_cvt_pk_bf16_f32 %0, %1, %2" : "=v"(r) : "v"(lo), "v"(hi_));
  return r;
}

// ------- fused fp32 -> bf16 conversion for hs + Wq + Wk + Wv + Wo (1 launch)
__global__ void cvt_all(const float* __restrict__ hs, const float* __restrict__ Wq,
                        const float* __restrict__ Wk, const float* __restrict__ Wv,
                        const float* __restrict__ Wo, u16* __restrict__ hs_bf,
                        u16* __restrict__ Wqkv_bf, u16* __restrict__ Wo_bf){
  int i = blockIdx.x*blockDim.x + threadIdx.x;   // 6291456 threads
  const float* s; u16* d;
  if (i < 1048576)      { s = hs + (size_t)i*8;            d = hs_bf  + (size_t)i*8; }
  else if (i < 3145728) { size_t j = i - 1048576; s = Wq + j*8; d = Wqkv_bf + j*8; }
  else if (i < 3670016) { size_t j = i - 3145728; s = Wk + j*8; d = Wqkv_bf + (size_t)(2097152 + j)*8; }
  else if (i < 4194304) { size_t j = i - 3670016; s = Wv + j*8; d = Wqkv_bf + (size_t)(2621440 + j)*8; }
  else                  { size_t j = i - 4194304; s = Wo + j*8; d = Wo_bf + j*8; }
  float4 a = *(const float4*)s, b = *(const float4*)(s + 4);
  union { u16 u[8]; uint4 v; } o;
  o.u[0]=f2bf(a.x); o.u[1]=f2bf(a.y); o.u[2]=f2bf(a.z); o.u[3]=f2bf(a.w);
  o.u[4]=f2bf(b.x); o.u[5]=f2bf(b.y); o.u[6]=f2bf(b.z); o.u[7]=f2bf(b.w);
  *(uint4*)d = o.v;
}

// ---------------- bias concat + rope tables ----------------
__global__ void setup_kernel(const float* __restrict__ bq, const float* __restrict__ bk,
                             const float* __restrict__ bv, const int* __restrict__ pos,
                             float* __restrict__ bqkv, float* __restrict__ cost,
                             float* __restrict__ sint){
  int i = blockIdx.x*blockDim.x + threadIdx.x;
  if (i < 6144) bqkv[i] = (i<4096) ? bq[i] : ((i<5120) ? bk[i-4096] : bv[i-5120]);
  if (i < T_SEQ*64){
    int t = i >> 6, d = i & 63;
    float inv = powf(10000.0f, -(float)(2*d) / 128.0f);
    float ang = (float)pos[t] * inv;
    cost[i] = cosf(ang);
    sint[i] = sinf(ang);
  }
}

#define GBAR __builtin_amdgcn_s_barrier()
#define LGKM0 do{ asm volatile("s_waitcnt lgkmcnt(0)" ::: "memory"); \
                  __builtin_amdgcn_sched_barrier(0); }while(0)

// ------- GEMM 256x192 4-phase (full-fill QKV): C = A[M,K]*B[N,K]^T + bias ---
#define BUF6 28672   // elems per buffer (A 16384 + B 12288)

#define AREAD6(mh, ck) do{ \
  const u16* ab = &lds[cur + aoff + (mh)*4096]; \
  afr[0] = *(const bf16x8_t*)&ab[0*1024 + (ck)]; \
  afr[1] = *(const bf16x8_t*)&ab[1*1024 + (ck)]; \
  afr[2] = *(const bf16x8_t*)&ab[2*1024 + (ck)]; \
  afr[3] = *(const bf16x8_t*)&ab[3*1024 + (ck)]; }while(0)

#define BREAD6(ck) do{ \
  const u16* bb = &lds[cur + boff]; \
  bfr[0] = *(const bf16x8_t*)&bb[0*1024 + (ck)]; \
  bfr[1] = *(const bf16x8_t*)&bb[1*1024 + (ck)]; \
  bfr[2] = *(const bf16x8_t*)&bb[2*1024 + (ck)]; }while(0)

#define MM12(mh) do{ \
  _Pragma("unroll") \
  for (int mi=0; mi<4; ++mi){ \
    _Pragma("unroll") \
    for (int n=0; n<3; ++n) \
      acc[(mh)*4+mi][n] = __builtin_amdgcn_mfma_f32_16x16x32_bf16(afr[mi], bfr[n], acc[(mh)*4+mi][n],0,0,0); \
  } }while(0)

__global__ __launch_bounds__(512, 2)
void gemm_qkv(const u16* __restrict__ A, const u16* __restrict__ B,
              const float* __restrict__ bias, u16* __restrict__ Cb,
              int K, int N)
{
  __shared__ u16 lds[2*BUF6];
  const int tid = threadIdx.x, lane = tid & 63, w = tid >> 6;
  const int l15 = lane & 15, l4 = lane >> 4;
  const int wm = w >> 2, wn = w & 3;

  const int nwg = gridDim.x * gridDim.y;   // 256
  int flat = blockIdx.y * gridDim.x + blockIdx.x;
  flat = (flat & 7) * (nwg >> 3) + (flat >> 3);
  const int bx = flat % gridDim.x, by = flat / gridDim.x;
  const int bm = by * 256, bn = bx * 192;

  const int srow = w*8 + (lane >> 3);
  const int swc  = ((lane & 7) ^ (lane >> 3)) * 8;
  const u16* pA = A + (size_t)(bm + srow)*K + swc;
  const u16* pB = B + (size_t)(bn + srow)*K + swc;
  const size_t j64 = (size_t)64*K;
  const int wu = w*512;

  const int cA0 = ((0 + l4) ^ (l15 & 7)) * 8;
  const int cA1 = ((4 + l4) ^ (l15 & 7)) * 8;
  const int aoff = (wm*128 + l15) * 64;
  const int boff = 16384 + (wn*48 + l15) * 64;

  f32x4_t acc[8][3] = {};
  const int KT = K >> 6;

  gload16(pA + 0*j64, &lds[0     + wu]);
  gload16(pA + 1*j64, &lds[4096  + wu]);
  gload16(pA + 2*j64, &lds[8192  + wu]);
  gload16(pA + 3*j64, &lds[12288 + wu]);
  gload16(pB + 0*j64, &lds[16384 + wu]);
  gload16(pB + 1*j64, &lds[20480 + wu]);
  gload16(pB + 2*j64, &lds[24576 + wu]);
  pA += 64; pB += 64;
  asm volatile("s_waitcnt vmcnt(0)" ::: "memory");
  GBAR;

  for (int t = 0; t < KT; ++t){
    const int cur = (t & 1) * BUF6;
    const int nxt = ((t + 1) & 1) * BUF6;
    const bool st = (t + 1 < KT);
    bf16x8_t afr[4], bfr[3];

    BREAD6(cA0); AREAD6(0, cA0);
    if (st){
      gload16(pA + 0*j64, &lds[nxt + 0     + wu]);
      gload16(pA + 1*j64, &lds[nxt + 4096  + wu]);
      gload16(pA + 2*j64, &lds[nxt + 8192  + wu]);
      gload16(pA + 3*j64, &lds[nxt + 12288 + wu]);
    }
    GBAR; LGKM0;
    __builtin_amdgcn_s_setprio(1); MM12(0); __builtin_amdgcn_s_setprio(0);
    GBAR;

    AREAD6(1, cA0);
    if (st){
      gload16(pB + 0*j64, &lds[nxt + 16384 + wu]);
      gload16(pB + 1*j64, &lds[nxt + 20480 + wu]);
      gload16(pB + 2*j64, &lds[nxt + 24576 + wu]);
      pA += 64; pB += 64;
    }
    GBAR; LGKM0;
    __builtin_amdgcn_s_setprio(1); MM12(1); __builtin_amdgcn_s_setprio(0);
    GBAR;

    BREAD6(cA1); AREAD6(0, cA1);
    GBAR; LGKM0;
    __builtin_amdgcn_s_setprio(1); MM12(0); __builtin_amdgcn_s_setprio(0);
    GBAR;

    AREAD6(1, cA1);
    GBAR; LGKM0;
    __builtin_amdgcn_s_setprio(1); MM12(1); __builtin_amdgcn_s_setprio(0);
    if (st) asm volatile("s_waitcnt vmcnt(0)" ::: "memory");
    GBAR;
  }

  #pragma unroll
  for (int m=0;m<8;m++){
    #pragma unroll
    for (int n=0;n<3;n++){
      #pragma unroll
      for (int j=0;j<4;j++){
        int row = bm + wm*128 + (m>>2)*64 + (m&3)*16 + l4*4 + j;
        int col = bn + wn*48 + n*16 + l15;
        Cb[(size_t)row*N + col] = f2bf(acc[m][n][j] + bias[col]);
      }
    }
  }
}

// ------- GEMM 256x128 2-phase tri-buffer (full-fill O-proj variant) ---------
#define BUFK 24576   // elems per buffer (A 16384 + B 8192)

#define KMREAD(ck) do{ \
  afr[0] = *(const bf16x8_t*)&lds[cur + aoff + 0*1024 + (ck)]; \
  afr[1] = *(const bf16x8_t*)&lds[cur + aoff + 1*1024 + (ck)]; \
  afr[2] = *(const bf16x8_t*)&lds[cur + aoff + 2*1024 + (ck)]; \
  afr[3] = *(const bf16x8_t*)&lds[cur + aoff + 3*1024 + (ck)]; \
  bfr[0] = *(const bf16x8_t*)&lds[cur + boff + 0*1024 + (ck)]; \
  bfr[1] = *(const bf16x8_t*)&lds[cur + boff + 1*1024 + (ck)]; \
  bfr[2] = *(const bf16x8_t*)&lds[cur + boff + 2*1024 + (ck)]; \
  bfr[3] = *(const bf16x8_t*)&lds[cur + boff + 3*1024 + (ck)]; }while(0)

#define MM16KM do{ \
  _Pragma("unroll") \
  for (int mi=0; mi<4; ++mi){ \
    _Pragma("unroll") \
    for (int n=0; n<4; ++n) \
      acc[mi][n] = __builtin_amdgcn_mfma_f32_16x16x32_bf16(afr[mi], bfr[n], acc[mi][n],0,0,0); \
  } }while(0)

__global__ __launch_bounds__(512, 2)
void gemm_km(const u16* __restrict__ A, const u16* __restrict__ B,
             const float* __restrict__ bias, float* __restrict__ Cf,
             int K, int N)
{
  __shared__ u16 lds[3*BUFK];
  const int tid = threadIdx.x, lane = tid & 63, w = tid >> 6;
  const int l15 = lane & 15, l4 = lane >> 4;
  const int wm = w >> 1, wn = w & 1;

  const int nwg = gridDim.x * gridDim.y;   // 256
  int flat = blockIdx.y * gridDim.x + blockIdx.x;
  flat = (flat & 7) * (nwg >> 3) + (flat >> 3);
  const int bx = flat % gridDim.x, by = flat / gridDim.x;
  const int bm = by * 256, bn = bx * 128;

  const int srow = w*8 + (lane >> 3);
  const int swc  = ((lane & 7) ^ (lane >> 3)) * 8;
  const u16* pA = A + (size_t)(bm + srow)*K + swc;
  const u16* pB = B + (size_t)(bn + srow)*K + swc;
  const size_t j64 = (size_t)64*K;
  const int wu = w*512;

  const int cA0 = ((0 + l4) ^ (l15 & 7)) * 8;
  const int cA1 = ((4 + l4) ^ (l15 & 7)) * 8;
  const int aoff = (wm*64 + l15) * 64;
  const int boff = 16384 + (wn*64 + l15) * 64;

  f32x4_t acc[4][4] = {};
  const int KT = K >> 6;

  gload16(pA + 0*j64,      &lds[0*4096 + wu]);
  gload16(pA + 1*j64,      &lds[1*4096 + wu]);
  gload16(pA + 2*j64,      &lds[2*4096 + wu]);
  gload16(pA + 3*j64,      &lds[3*4096 + wu]);
  gload16(pB + 0*j64,      &lds[16384 + 0*4096 + wu]);
  gload16(pB + 1*j64,      &lds[16384 + 1*4096 + wu]);
  gload16(pA + 64 + 0*j64, &lds[BUFK + 0*4096 + wu]);
  gload16(pA + 64 + 1*j64, &lds[BUFK + 1*4096 + wu]);
  gload16(pA + 64 + 2*j64, &lds[BUFK + 2*4096 + wu]);
  gload16(pA + 64 + 3*j64, &lds[BUFK + 3*4096 + wu]);
  gload16(pB + 64 + 0*j64, &lds[BUFK + 16384 + 0*4096 + wu]);
  gload16(pB + 64 + 1*j64, &lds[BUFK + 16384 + 1*4096 + wu]);
  pA += 128; pB += 128;
  asm volatile("s_waitcnt vmcnt(6)" ::: "memory");
  GBAR;

  for (int t = 0; t < KT; ++t){
    const int cur = (t % 3) * BUFK;
    const int sb  = ((t + 2) % 3) * BUFK;
    const bool st = (t + 2 < KT);
    bf16x8_t afr[4], bfr[4];

    KMREAD(cA0);
    if (st){
      gload16(pA + 0*j64, &lds[sb + 0*4096 + wu]);
      gload16(pA + 1*j64, &lds[sb + 1*4096 + wu]);
      gload16(pA + 2*j64, &lds[sb + 2*4096 + wu]);
    }
    GBAR; LGKM0;
    __builtin_amdgcn_s_setprio(1); MM16KM; __builtin_amdgcn_s_setprio(0);
    GBAR;

    KMREAD(cA1);
    if (st){
      gload16(pA + 3*j64, &lds[sb + 3*4096 + wu]);
      gload16(pB + 0*j64, &lds[sb + 16384 + 0*4096 + wu]);
      gload16(pB + 1*j64, &lds[sb + 16384 + 1*4096 + wu]);
      pA += 64; pB += 64;
    }
    GBAR; LGKM0;
    __builtin_amdgcn_s_setprio(1); MM16KM; __builtin_amdgcn_s_setprio(0);
    if (st)              asm volatile("s_waitcnt vmcnt(6)" ::: "memory");
    else if (t + 1 < KT) asm volatile("s_waitcnt vmcnt(0)" ::: "memory");
    GBAR;
  }

  #pragma unroll
  for (int mi=0;mi<4;mi++){
    #pragma unroll
    for (int n=0;n<4;n++){
      #pragma unroll
      for (int j=0;j<4;j++){
        int row = bm + wm*64 + mi*16 + l4*4 + j;
        int col = bn + wn*64 + n*16 + l15;
        Cf[(size_t)row*N + col] = acc[mi][n][j] + bias[col];
      }
    }
  }
}

// ---------------- RoPE in-place on q (heads 0..31) and k (heads 32..39) -----
__global__ void rope_kernel(u16* __restrict__ qkv, const float* __restrict__ cost,
                            const float* __restrict__ sint){
  int i = blockIdx.x*blockDim.x + threadIdx.x;
  int t = i / 2560;
  int r = i % 2560;
  int h = r >> 6, d = r & 63;
  int base = (h < 32) ? h*128 : (4096 + (h-32)*128);
  size_t p1 = (size_t)t*ROWQKV + base + d;
  float x1 = bf2f(qkv[p1]), x2 = bf2f(qkv[p1+64]);
  float c = cost[(t<<6)+d], s = sint[(t<<6)+d];
  qkv[p1]    = f2bf(x1*c - x2*s);
  qkv[p1+64] = f2bf(x2*c + x1*s);
}

// ---------------- flash attention (r16: two-barrier + ones-column row-sum) --
#define VOFF 16384
#define POFF 25600

__global__ __launch_bounds__(256, 2)
void attn_kernel(const u16* __restrict__ qkv, u16* __restrict__ attn_o)
{
  __shared__ u16 lds[29696];   // 58 KB
  const int tid = threadIdx.x, lane = tid&63, wid = tid>>6;
  const int l15 = lane&15, l4 = lane>>4;
  const int l7 = l15 & 7;
  const int h  = blockIdx.x & 31;
  const int qt = 31 - (blockIdx.x >> 5);       // heavy tiles first
  const int q0 = qt * 64;
  const int kvh = h >> 2;
  const u16* Qg = qkv + h*128;
  const u16* Kg = qkv + 4096 + kvh*128;
  const u16* Vg = qkv + 5120 + kvh*128;
  const float c2 = 0.127543147f;               // (1/sqrt(128)) * log2(e)

  bf16x8_t qf[4];
  {
    size_t qrow = (size_t)(q0 + wid*16 + l15);
    #pragma unroll
    for (int kk=0;kk<4;kk++)
      qf[kk] = *(const bf16x8_t*)(Qg + qrow*ROWQKV + kk*32 + l4*8);
  }
  float mrow[4] = {-1e30f,-1e30f,-1e30f,-1e30f};   // raw-score units
  f32x4_t oacc[9] = {};                            // [8] = row-sum (ones col)

  const u16* ksrc[4];
  int kls[4];
  #pragma unroll
  for (int i=0;i<4;i++){
    const int c = wid*4 + i;
    ksrc[i] = Kg + (size_t)((c&7)*8 + (lane>>3))*ROWQKV
               + (c>>3)*64 + ((lane&7)^(lane>>3))*8;
    kls[i] = c*512;
  }
  const int kvp = tid & 31;
  const int vd0 = (tid >> 5) * 16;
  uint4 rv[4];

  #pragma unroll
  for (int i=0;i<4;i++) gload16(ksrc[i], &lds[kls[i]]);
  #pragma unroll
  for (int i=0;i<4;i++) ksrc[i] += (size_t)64*ROWQKV;
  {
    const u16* va = Vg + (size_t)(2*kvp)*ROWQKV + vd0;
    rv[0] = *(const uint4*)va;            rv[1] = *(const uint4*)(va + 8);
    rv[2] = *(const uint4*)(va + ROWQKV); rv[3] = *(const uint4*)(va + ROWQKV + 8);
    *(uint32_t*)&lds[24576 + tid*4]     = 0x3F803F80u;
    *(uint32_t*)&lds[24576 + tid*4 + 2] = 0x3F803F80u;
  }
  __syncthreads();
  {
    const u16* ra = (const u16*)&rv[0]; const u16* rb = (const u16*)&rv[2];
    #pragma unroll
    for (int e=0;e<8;e++)
      *(uint32_t*)&lds[VOFF + (vd0+e)*64 + ((kvp>>2)^(e&7))*8 + 2*(kvp&3)]
          = (uint32_t)ra[e] | ((uint32_t)rb[e] << 16);
    ra = (const u16*)&rv[1]; rb = (const u16*)&rv[3];
    #pragma unroll
    for (int e=0;e<8;e++)
      *(uint32_t*)&lds[VOFF + (vd0+8+e)*64 + ((kvp>>2)^(e&7))*8 + 2*(kvp&3)]
          = (uint32_t)ra[e] | ((uint32_t)rb[e] << 16);
  }
  __syncthreads();

  for (int kt = 0; kt <= qt; ++kt){
    const int kv0 = kt * 64;
    const int kcur = (kt & 1) * 8192;
    const bool pre = (kt < qt);
    if (pre){
      const int knxt = ((kt+1) & 1) * 8192;
      #pragma unroll
      for (int i=0;i<4;i++) gload16(ksrc[i], &lds[knxt + kls[i]]);
      #pragma unroll
      for (int i=0;i<4;i++) ksrc[i] += (size_t)64*ROWQKV;
      const u16* va = Vg + (size_t)(kv0 + 64 + 2*kvp)*ROWQKV + vd0;
      rv[0] = *(const uint4*)va;            rv[1] = *(const uint4*)(va + 8);
      rv[2] = *(const uint4*)(va + ROWQKV); rv[3] = *(const uint4*)(va + ROWQKV + 8);
    }

    // S = Q K^T (raw scores)
    f32x4_t sacc[4] = {};
    __builtin_amdgcn_s_setprio(1);
    #pragma unroll
    for (int n=0;n<4;n++){
      #pragma unroll
      for (int kk=0;kk<4;kk++){
        bf16x8_t kf = *(const bf16x8_t*)&lds[kcur + (kk>>1)*4096
                        + (n*16+l15)*64 + (((kk&1)*4 + l4) ^ l7)*8];
        sacc[n] = __builtin_amdgcn_mfma_f32_16x16x32_bf16(qf[kk], kf, sacc[n], 0,0,0);
      }
    }
    __builtin_amdgcn_s_setprio(0);
    float sv[4][4];
    float pmax[4] = {-1e30f,-1e30f,-1e30f,-1e30f};
    bool diag = (kt == qt);
    #pragma unroll
    for (int n=0;n<4;n++){
      int kvcol = kv0 + n*16 + l15;
      #pragma unroll
      for (int j=0;j<4;j++){
        float s = sacc[n][j];
        int qrow = q0 + wid*16 + l4*4 + j;
        if (diag && kvcol > qrow) s = -1e30f;
        sv[n][j] = s;
        pmax[j] = fmaxf(pmax[j], s);
      }
    }
    #pragma unroll
    for (int off=1; off<16; off<<=1){
      #pragma unroll
      for (int j=0;j<4;j++)
        pmax[j] = fmaxf(pmax[j], __shfl_xor(pmax[j], off, 64));
    }
    float esc[4], mc[4];
    #pragma unroll
    for (int j=0;j<4;j++){
      float mn = fmaxf(mrow[j], pmax[j]);
      esc[j] = exp2f((mrow[j] - mn) * c2);
      mrow[j] = mn;
      mc[j] = mn * c2;
    }
    #pragma unroll
    for (int n=0;n<4;n++){
      #pragma unroll
      for (int j=0;j<4;j++)
        sv[n][j] = exp2f(fmaf(sv[n][j], c2, -mc[j]));
    }
    #pragma unroll
    for (int n=0;n<9;n++){
      #pragma unroll
      for (int j=0;j<4;j++) oacc[n][j] *= esc[j];
    }
    // P -> LDS via cvt_pk, swizzled wave-private strip
    {
      const int r0 = wid*16 + l4*4;
      #pragma unroll
      for (int n=0;n<4;n++){
        uint32_t p01 = cvtpk(sv[n][0], sv[n][1]);
        uint32_t p23 = cvtpk(sv[n][2], sv[n][3]);
        const int cb = n*2 + (l15>>3);
        lds[POFF + (r0+0)*64 + ((cb ^ ((r0+0)&7))*8) + l7] = (u16)p01;
        lds[POFF + (r0+1)*64 + ((cb ^ ((r0+1)&7))*8) + l7] = (u16)(p01 >> 16);
        lds[POFF + (r0+2)*64 + ((cb ^ ((r0+2)&7))*8) + l7] = (u16)p23;
        lds[POFF + (r0+3)*64 + ((cb ^ ((r0+3)&7))*8) + l7] = (u16)(p23 >> 16);
      }
    }
    // O += P V  (n=8 reads the ones rows -> row-sum accumulates in oacc[8])
    __builtin_amdgcn_s_setprio(1);
    #pragma unroll
    for (int kk=0;kk<2;kk++){
      const int blk = ((kk*4 + l4) ^ l7)*8;
      bf16x8_t pf = *(const bf16x8_t*)&lds[POFF + (wid*16 + l15)*64 + blk];
      #pragma unroll
      for (int n=0;n<9;n++){
        bf16x8_t vf = *(const bf16x8_t*)&lds[VOFF + (n*16 + l15)*64 + blk];
        oacc[n] = __builtin_amdgcn_mfma_f32_16x16x32_bf16(pf, vf, oacc[n], 0,0,0);
      }
    }
    __builtin_amdgcn_s_setprio(0);
    __syncthreads();
    if (pre){
      const u16* ra = (const u16*)&rv[0]; const u16* rb = (const u16*)&rv[2];
      #pragma unroll
      for (int e=0;e<8;e++)
        *(uint32_t*)&lds[VOFF + (vd0+e)*64 + ((kvp>>2)^(e&7))*8 + 2*(kvp&3)]
            = (uint32_t)ra[e] | ((uint32_t)rb[e] << 16);
      ra = (const u16*)&rv[1]; rb = (const u16*)&rv[3];
      #pragma unroll
      for (int e=0;e<8;e++)
        *(uint32_t*)&lds[VOFF + (vd0+8+e)*64 + ((kvp>>2)^(e&7))*8 + 2*(kvp&3)]
            = (uint32_t)ra[e] | ((uint32_t)rb[e] << 16);
    }
    __syncthreads();
  }

  {
    float inv[4];
    #pragma unroll
    for (int j=0;j<4;j++) inv[j] = 1.0f / oacc[8][j];
    #pragma unroll
    for (int n=0;n<8;n++){
      #pragma unroll
      for (int j=0;j<4;j++){
        int qrow = q0 + wid*16 + l4*4 + j;
        int col  = h*128 + n*16 + l15;
        attn_o[(size_t)qrow*HID + col] = f2bf(oacc[n][j] * inv[j]);
      }
    }
  }
}

// ---------------- launcher ----------------
extern "C" void kernel_launch(void* const* d_in, const int* in_sizes, int n_in,
                              void* d_out, int out_size, void* d_ws, size_t ws_size,
                              hipStream_t stream)
{
  const float* hs = (const float*)d_in[0];
  const int*  pos = (const int*)d_in[1];
  const float* Wq = (const float*)d_in[2];
  const float* bq = (const float*)d_in[3];
  const float* Wk = (const float*)d_in[4];
  const float* bk = (const float*)d_in[5];
  const float* Wv = (const float*)d_in[6];
  const float* bv = (const float*)d_in[7];
  const float* Wo = (const float*)d_in[8];
  const float* bo = (const float*)d_in[9];
  float* out = (float*)d_out;

  char* ws = (char*)d_ws;
  u16* hs_bf   = (u16*)ws;  ws += (size_t)2048*4096*2;
  u16* Wqkv_bf = (u16*)ws;  ws += (size_t)6144*4096*2;
  u16* Wo_bf   = (u16*)ws;  ws += (size_t)4096*4096*2;
  u16* qkv     = (u16*)ws;  ws += (size_t)2048*6144*2;
  u16* attn_b  = (u16*)ws;  ws += (size_t)2048*4096*2;
  float* bqkv  = (float*)ws; ws += (size_t)6144*4;
  float* cost  = (float*)ws; ws += (size_t)2048*64*4;
  float* sint  = (float*)ws; ws += (size_t)2048*64*4;

  // all fp32 -> bf16 conversions in ONE dispatch (6291456 groups of 8)
  cvt_all<<<6291456/256, 256, 0, stream>>>(hs, Wq, Wk, Wv, Wo, hs_bf, Wqkv_bf, Wo_bf);
  setup_kernel<<<(T_SEQ*64 + 255)/256, 256, 0, stream>>>(bq, bk, bv, pos, bqkv, cost, sint);

  // QKV projection: [2048,6144] — 256x192 tiles, grid 32x8 = 256 blocks
  gemm_qkv<<<dim3(6144/192, 2048/256), 512, 0, stream>>>(hs_bf, Wqkv_bf, bqkv, qkv, 4096, 6144);
  // RoPE on q,k
  rope_kernel<<<(T_SEQ*40*64)/256, 256, 0, stream>>>(qkv, cost, sint);
  // attention
  attn_kernel<<<1024, 256, 0, stream>>>(qkv, attn_b);
  // output projection: [2048,4096] — 256x128 tiles, grid 32x8 = 256 blocks
  gemm_km<<<dim3(4096/128, 2048/256), 512, 0, stream>>>(attn_b, Wo_bf, bo, out, 4096, 4096);
}